// Round 1
// baseline (1716.585 us; speedup 1.0000x reference)
//
#include <hip/hip_runtime.h>
#include <stdint.h>

// SAINT encoder: B=32 S=512 D=512 H=8 DH=64 F=2048 L=4
// Strategy: bf16 MFMA (16x16x32) for all GEMMs + flash attention, f32 residual stream.
#define B_ 32
#define S_ 512
#define D_ 512
#define H_ 8
#define F_ 2048
#define L_ 4
#define DH_ 64
#define M_ (B_*S_)   // 16384 rows

typedef unsigned short u16;
typedef float f32x4 __attribute__((ext_vector_type(4)));
typedef short bf16x8 __attribute__((ext_vector_type(8)));

__device__ __forceinline__ u16 f2b(float f) {
  unsigned u = __float_as_uint(f);
  u += 0x7FFFu + ((u >> 16) & 1u);          // round-to-nearest-even
  return (u16)(u >> 16);
}

__device__ __forceinline__ void gld16(const void* g, void* l) {
  // async global->LDS, 16B per lane; LDS dest is wave-uniform base + lane*16
  __builtin_amdgcn_global_load_lds((__attribute__((address_space(1))) void*)(void*)g,
                                   (__attribute__((address_space(3))) void*)l, 16, 0, 0);
}

__device__ __forceinline__ f32x4 mfma16(bf16x8 a, bf16x8 b, f32x4 c) {
  return __builtin_amdgcn_mfma_f32_16x16x32_bf16(a, b, c, 0, 0, 0);
}

__device__ __forceinline__ float gelu_exact(float x) {
  return 0.5f * x * (1.0f + erff(x * 0.70710678118654752f));
}

// ---------------- weight transpose + bf16 convert: W[R][C] f32 -> WT[C][R] bf16 ----
__global__ __launch_bounds__(256) void transpose_w(const float* __restrict__ in,
                                                   u16* __restrict__ out, int R, int C) {
  __shared__ float tile[32][33];
  const int l = blockIdx.z;
  in  += (size_t)l * R * C;
  out += (size_t)l * R * C;
  const int c0 = blockIdx.x * 32, r0 = blockIdx.y * 32;
  const int tx = threadIdx.x, ty = threadIdx.y;
#pragma unroll
  for (int k = 0; k < 4; k++)
    tile[ty + 8*k][tx] = in[(size_t)(r0 + ty + 8*k) * C + c0 + tx];
  __syncthreads();
#pragma unroll
  for (int k = 0; k < 4; k++)
    out[(size_t)(c0 + ty + 8*k) * R + r0 + tx] = f2b(tile[tx][ty + 8*k]);
}

// ---------------- x init: copy hidden -> x (f32, in d_out) and xb (bf16) ----------
__global__ __launch_bounds__(256) void prep_x(const float* __restrict__ h,
                                              float* __restrict__ x, u16* __restrict__ xb) {
  int i = blockIdx.x * 256 + threadIdx.x;   // grid sized exactly: n/4 elements of float4
  float4 v = ((const float4*)h)[i];
  ((float4*)x)[i] = v;
  ushort4 u; u.x = f2b(v.x); u.y = f2b(v.y); u.z = f2b(v.z); u.w = f2b(v.w);
  ((ushort4*)xb)[i] = u;
}

// ---------------- GEMM: C[M,N] = A[M,K](bf16) * B[K,N] via BT[N,K](bf16) ----------
// 128x128 tile, BK=32, 4 waves each 64x64 (4x4 MFMA tiles). m97 structure.
// epi: 0 = bf16 out (+bias); 1 = f32 out (+bias+residual); 2 = bf16 gelu(+bias);
//      3 = bf16 out in transposed V layout [B,H,DH,S] (+bias)
__device__ __forceinline__ void gemm_core(
    const u16* __restrict__ A, const u16* __restrict__ BT,
    const int N, const int K,
    const float* __restrict__ bias, const float* __restrict__ res,
    float* __restrict__ outf, u16* __restrict__ outb, const int epi)
{
  __shared__ u16 As[128*32];
  __shared__ u16 Bs[128*32];
  const int tid = threadIdx.x;
  const int wid = tid >> 6, lane = tid & 63;
  const int wm = (wid >> 1) * 64, wn = (wid & 1) * 64;
  const int lr = lane & 15, quad = lane >> 4;
  const int m0 = blockIdx.x * 128, n0 = blockIdx.y * 128;

  f32x4 acc[4][4];
#pragma unroll
  for (int i = 0; i < 4; i++)
#pragma unroll
    for (int j = 0; j < 4; j++) acc[i][j] = (f32x4){0.f, 0.f, 0.f, 0.f};

  const u16* Ag = A  + (size_t)(m0 + wid*16 + (lane>>2))*K + (lane&3)*8;
  const u16* Bg = BT + (size_t)(n0 + wid*16 + (lane>>2))*K + (lane&3)*8;
  u16* AsW = As + wid*512;   // per-wave LDS staging base (bytes: wid*1024)
  u16* BsW = Bs + wid*512;
  const size_t rskip = (size_t)64*K;

  for (int k0 = 0; k0 < K; k0 += 32) {
    gld16(Ag + k0,         AsW);
    gld16(Ag + rskip + k0, AsW + 2048);
    gld16(Bg + k0,         BsW);
    gld16(Bg + rskip + k0, BsW + 2048);
    __syncthreads();
    bf16x8 af[4], bfr[4];
#pragma unroll
    for (int i = 0; i < 4; i++) af[i]  = *(const bf16x8*)(As + (wm + i*16 + lr)*32 + quad*8);
#pragma unroll
    for (int j = 0; j < 4; j++) bfr[j] = *(const bf16x8*)(Bs + (wn + j*16 + lr)*32 + quad*8);
#pragma unroll
    for (int i = 0; i < 4; i++)
#pragma unroll
      for (int j = 0; j < 4; j++)
        acc[i][j] = mfma16(af[i], bfr[j], acc[i][j]);
    __syncthreads();
  }

  // epilogue; D element (row = quad*4+r, col = lr) per 16x16 tile
#pragma unroll
  for (int j = 0; j < 4; j++) {
    const int n = n0 + wn + j*16 + lr;
    const float bn = bias[n];
#pragma unroll
    for (int i = 0; i < 4; i++) {
      const int mb = m0 + wm + i*16 + quad*4;
#pragma unroll
      for (int r = 0; r < 4; r++) {
        const int m = mb + r;
        float v = acc[i][j][r] + bn;
        if (epi == 0) {
          outb[(size_t)m*N + n] = f2b(v);
        } else if (epi == 1) {
          outf[(size_t)m*N + n] = v + res[(size_t)m*N + n];
        } else if (epi == 2) {
          outb[(size_t)m*N + n] = f2b(gelu_exact(v));
        } else {
          const int bb_ = m >> 9, sr = m & 511, hh = n >> 6, dd = n & 63;
          outb[(((size_t)((bb_*H_ + hh)*DH_ + dd)) << 9) + sr] = f2b(v);
        }
      }
    }
  }
}

__global__ __launch_bounds__(256) void gemm_kernel(
    const u16* A, const u16* BT, int N, int K,
    const float* bias, const float* res, float* outf, u16* outb, int epi)
{
  gemm_core(A, BT, N, K, bias, res, outf, outb, epi);
}

__global__ __launch_bounds__(256) void gemm_qkv_kernel(
    const u16* A, const u16* BTq, size_t zstride, int K,
    const float* b0, const float* b1, const float* b2,
    u16* out0, u16* out1, u16* out2)
{
  const int z = blockIdx.z;
  const u16* BT = BTq + (size_t)z * zstride;
  const float* bias = (z == 0) ? b0 : (z == 1) ? b1 : b2;
  u16* outb = (z == 0) ? out0 : (z == 1) ? out1 : out2;
  gemm_core(A, BT, 512, K, bias, nullptr, nullptr, outb, (z == 2) ? 3 : 0);
}

// ---------------- LayerNorm: one wave per row of 512 ------------------------------
__global__ __launch_bounds__(256) void ln_kernel(
    const float* __restrict__ y, const float* __restrict__ g, const float* __restrict__ bta,
    float* __restrict__ outf, u16* __restrict__ outb)
{
  const int lane = threadIdx.x & 63;
  const int row = blockIdx.x*4 + (threadIdx.x >> 6);
  const float* yr = y + (size_t)row*D_ + lane*8;
  float4 a0 = *(const float4*)yr;
  float4 a1 = *(const float4*)(yr + 4);
  float v[8] = {a0.x, a0.y, a0.z, a0.w, a1.x, a1.y, a1.z, a1.w};
  float s = 0.f;
#pragma unroll
  for (int e = 0; e < 8; e++) s += v[e];
#pragma unroll
  for (int m = 1; m < 64; m <<= 1) s += __shfl_xor(s, m);
  const float mu = s * (1.0f/512.0f);
  float q = 0.f;
#pragma unroll
  for (int e = 0; e < 8; e++) { float d = v[e] - mu; q += d*d; }
#pragma unroll
  for (int m = 1; m < 64; m <<= 1) q += __shfl_xor(q, m);
  const float rs = rsqrtf(q * (1.0f/512.0f) + 1e-12f);
  float4 g0 = *(const float4*)(g + lane*8);
  float4 g1 = *(const float4*)(g + lane*8 + 4);
  float4 b0 = *(const float4*)(bta + lane*8);
  float4 b1 = *(const float4*)(bta + lane*8 + 4);
  float gg[8] = {g0.x, g0.y, g0.z, g0.w, g1.x, g1.y, g1.z, g1.w};
  float bb[8] = {b0.x, b0.y, b0.z, b0.w, b1.x, b1.y, b1.z, b1.w};
  float o[8];
#pragma unroll
  for (int e = 0; e < 8; e++) o[e] = (v[e] - mu) * rs * gg[e] + bb[e];
  float4 w0 = {o[0], o[1], o[2], o[3]}, w1 = {o[4], o[5], o[6], o[7]};
  *(float4*)(outf + (size_t)row*D_ + lane*8)     = w0;
  *(float4*)(outf + (size_t)row*D_ + lane*8 + 4) = w1;
  ushort4 u0 = {f2b(o[0]), f2b(o[1]), f2b(o[2]), f2b(o[3])};
  ushort4 u1 = {f2b(o[4]), f2b(o[5]), f2b(o[6]), f2b(o[7])};
  *(ushort4*)(outb + (size_t)row*D_ + lane*8)     = u0;
  *(ushort4*)(outb + (size_t)row*D_ + lane*8 + 4) = u1;
}

// ---------------- flash attention: block = (i-tile 64 rows, head, batch) ----------
__global__ __launch_bounds__(256) void attn_kernel(
    const u16* __restrict__ qb, const u16* __restrict__ kb, const u16* __restrict__ vt,
    const float* __restrict__ pbias, const int* __restrict__ ts, u16* __restrict__ cb)
{
  __shared__ u16 Qs[64*64], Ks[64*64], Vs[64*64];   // Vs holds VT tile [d][j-local]
  __shared__ u16 Ps[4][16*64];                      // per-wave P roundtrip
  __shared__ int Ti[64], Tj[64];
  const int it = blockIdx.x, h = blockIdx.y, b = blockIdx.z;
  const int i0 = it * 64;
  const int tid = threadIdx.x, wid = tid >> 6, lane = tid & 63;
  const int lr = lane & 15, quad = lane >> 4;
  const u16* qg = qb + ((size_t)(b*S_ + i0))*D_ + h*DH_;
  const u16* kg = kb + ((size_t)b*S_)*D_ + h*DH_;
  const u16* vg = vt + ((size_t)(b*H_ + h)*DH_)*S_;       // rows d (64), cols j (512)

  {
    const int rr = wid*8 + (lane >> 3), cc = (lane & 7)*8;
    gld16(qg + (size_t)rr*D_ + cc,        Qs + wid*512);
    gld16(qg + (size_t)(rr+32)*D_ + cc,   Qs + 2048 + wid*512);
  }
  if (tid < 64) Ti[tid] = ts[b*S_ + i0 + tid];
  __syncthreads();

  bf16x8 aq0 = *(const bf16x8*)(Qs + (wid*16 + lr)*64 + quad*8);
  bf16x8 aq1 = *(const bf16x8*)(Qs + (wid*16 + lr)*64 + 32 + quad*8);

  float mrow[4], lrow[4];
  f32x4 O[4];
#pragma unroll
  for (int r = 0; r < 4; r++) { mrow[r] = -1e30f; lrow[r] = 0.f; }
#pragma unroll
  for (int dt = 0; dt < 4; dt++) O[dt] = (f32x4){0.f, 0.f, 0.f, 0.f};
  const float inv_min = 1.0f / 60000.0f;

  for (int t8 = 0; t8 < 8; t8++) {
    const int j0 = t8 * 64;
    {
      const int rr = wid*8 + (lane >> 3), cc = (lane & 7)*8;
      gld16(kg + (size_t)(j0+rr)*D_ + cc,        Ks + wid*512);
      gld16(kg + (size_t)(j0+rr+32)*D_ + cc,     Ks + 2048 + wid*512);
      gld16(vg + (size_t)rr*S_ + j0 + cc,        Vs + wid*512);
      gld16(vg + (size_t)(rr+32)*S_ + j0 + cc,   Vs + 2048 + wid*512);
    }
    if (tid < 64) Tj[tid] = ts[b*S_ + j0 + tid];
    __syncthreads();

    // S = Q K^T (16 rows x 64 cols per wave)
    f32x4 s[4];
#pragma unroll
    for (int jt = 0; jt < 4; jt++) {
      bf16x8 bk0 = *(const bf16x8*)(Ks + (jt*16 + lr)*64 + quad*8);
      bf16x8 bk1 = *(const bf16x8*)(Ks + (jt*16 + lr)*64 + 32 + quad*8);
      f32x4 z = (f32x4){0.f, 0.f, 0.f, 0.f};
      z = mfma16(aq0, bk0, z);
      z = mfma16(aq1, bk1, z);
      s[jt] = z;
    }
    // scale (from timestamps) + position bias
    const int ibase = i0 + wid*16 + quad*4;
#pragma unroll
    for (int jt = 0; jt < 4; jt++) {
      const int jg = j0 + jt*16 + lr;
      const int tj = Tj[jt*16 + lr];
#pragma unroll
      for (int r = 0; r < 4; r++) {
        float lag = (float)(Ti[wid*16 + quad*4 + r] - tj) * inv_min;
        lag = fmaxf(lag, 0.f);
        float sc = 9.0f - __builtin_amdgcn_rcpf(lag + 1.0f);   // sqrt(64)-1/(lag+1)+1
        float pb = pbias[((size_t)h*S_ + (ibase + r))*S_ + jg];
        s[jt][r] = s[jt][r] * __builtin_amdgcn_rcpf(sc) + pb;
      }
    }
    // online softmax (rows quad*4+r shared by the 16 lanes with equal quad)
#pragma unroll
    for (int r = 0; r < 4; r++) {
      float rmax = fmaxf(fmaxf(s[0][r], s[1][r]), fmaxf(s[2][r], s[3][r]));
#pragma unroll
      for (int msk = 1; msk < 16; msk <<= 1) rmax = fmaxf(rmax, __shfl_xor(rmax, msk));
      float mn = fmaxf(mrow[r], rmax);
      float alpha = __expf(mrow[r] - mn);
      mrow[r] = mn;
      float rsum = 0.f;
#pragma unroll
      for (int jt = 0; jt < 4; jt++) {
        float p = __expf(s[jt][r] - mn);
        s[jt][r] = p;
        rsum += p;
      }
#pragma unroll
      for (int msk = 1; msk < 16; msk <<= 1) rsum += __shfl_xor(rsum, msk);
      lrow[r] = lrow[r]*alpha + rsum;
#pragma unroll
      for (int dt = 0; dt < 4; dt++) O[dt][r] *= alpha;
    }
    // P -> LDS (C-layout -> A-operand layout roundtrip, per-wave region)
#pragma unroll
    for (int jt = 0; jt < 4; jt++)
#pragma unroll
      for (int r = 0; r < 4; r++)
        Ps[wid][(quad*4 + r)*64 + jt*16 + lr] = f2b(s[jt][r]);
    bf16x8 ap0 = *(const bf16x8*)(&Ps[wid][lr*64 + quad*8]);
    bf16x8 ap1 = *(const bf16x8*)(&Ps[wid][lr*64 + 32 + quad*8]);
#pragma unroll
    for (int dt = 0; dt < 4; dt++) {
      bf16x8 bv0 = *(const bf16x8*)(Vs + (dt*16 + lr)*64 + quad*8);
      bf16x8 bv1 = *(const bf16x8*)(Vs + (dt*16 + lr)*64 + 32 + quad*8);
      O[dt] = mfma16(ap0, bv0, O[dt]);
      O[dt] = mfma16(ap1, bv1, O[dt]);
    }
    __syncthreads();
  }

#pragma unroll
  for (int r = 0; r < 4; r++) {
    const float inv_l = __builtin_amdgcn_rcpf(lrow[r]);
    const int ig = i0 + wid*16 + quad*4 + r;
#pragma unroll
    for (int dt = 0; dt < 4; dt++)
      cb[((size_t)(b*S_ + ig))*D_ + h*DH_ + dt*16 + lr] = f2b(O[dt][r] * inv_l);
  }
}

// ---------------- orchestration ----------------------------------------------------
extern "C" void kernel_launch(void* const* d_in, const int* in_sizes, int n_in,
                              void* d_out, int out_size, void* d_ws, size_t ws_size,
                              hipStream_t stream)
{
  const float* hidden = (const float*)d_in[0];
  const float* pbias  = (const float*)d_in[1];
  const int*   ts     = (const int*)d_in[2];   // jax default x64-off: int32
  const float* Wq = (const float*)d_in[3];   const float* bq  = (const float*)d_in[4];
  const float* Wk = (const float*)d_in[5];   const float* bk  = (const float*)d_in[6];
  const float* Wv = (const float*)d_in[7];   const float* bv  = (const float*)d_in[8];
  const float* Wo = (const float*)d_in[9];   const float* bo  = (const float*)d_in[10];
  const float* l1g = (const float*)d_in[11]; const float* l1b = (const float*)d_in[12];
  const float* Wi = (const float*)d_in[13];  const float* bi  = (const float*)d_in[14];
  const float* Wf = (const float*)d_in[15];  const float* bfw = (const float*)d_in[16];
  const float* l2g = (const float*)d_in[17]; const float* l2b = (const float*)d_in[18];

  char* w = (char*)d_ws;
  u16* xb    = (u16*)w; w += (size_t)M_*D_*2;
  u16* qb    = (u16*)w; w += (size_t)M_*D_*2;
  u16* kbuf  = (u16*)w; w += (size_t)M_*D_*2;
  u16* vtw   = (u16*)w; w += (size_t)M_*D_*2;
  u16* cbuf  = (u16*)w; w += (size_t)M_*D_*2;
  u16* attnb = (u16*)w; w += (size_t)M_*D_*2;
  float* yf    = (float*)w; w += (size_t)M_*D_*4;
  float* attnf = (float*)w; w += (size_t)M_*D_*4;
  u16* WqkvT = (u16*)w; w += (size_t)3*L_*D_*D_*2;
  u16* WoT   = (u16*)w; w += (size_t)L_*D_*D_*2;
  u16* WiT   = (u16*)w; w += (size_t)L_*D_*F_*2;
  u16* WfT   = (u16*)w; w += (size_t)L_*F_*D_*2;
  u16* hb    = qb;   // alias: qb..cbuf span 4*16MB = exactly M_*F_ bf16; lifetimes disjoint

  float* x = (float*)d_out;   // f32 residual stream lives in d_out

  const size_t WD = (size_t)D_*D_;
  const size_t WF = (size_t)D_*F_;
  dim3 tb(32, 8);

  transpose_w<<<dim3(16,16,L_), tb, 0, stream>>>(Wq, WqkvT,           D_, D_);
  transpose_w<<<dim3(16,16,L_), tb, 0, stream>>>(Wk, WqkvT + L_*WD,   D_, D_);
  transpose_w<<<dim3(16,16,L_), tb, 0, stream>>>(Wv, WqkvT + 2*L_*WD, D_, D_);
  transpose_w<<<dim3(16,16,L_), tb, 0, stream>>>(Wo, WoT,             D_, D_);
  transpose_w<<<dim3(64,16,L_), tb, 0, stream>>>(Wi, WiT,             D_, F_);
  transpose_w<<<dim3(16,64,L_), tb, 0, stream>>>(Wf, WfT,             F_, D_);
  prep_x<<<dim3(8192), dim3(256), 0, stream>>>(hidden, x, xb);

  for (int l = 0; l < L_; l++) {
    gemm_qkv_kernel<<<dim3(128,4,3), dim3(256), 0, stream>>>(
        xb, WqkvT + l*WD, (size_t)L_*WD, D_,
        bq + l*D_, bk + l*D_, bv + l*D_, qb, kbuf, vtw);
    attn_kernel<<<dim3(8,H_,B_), dim3(256), 0, stream>>>(qb, kbuf, vtw, pbias, ts, cbuf);
    gemm_kernel<<<dim3(128,4), dim3(256), 0, stream>>>(
        cbuf, WoT + l*WD, D_, D_, bo + l*D_, x, yf, (u16*)nullptr, 1);
    ln_kernel<<<dim3(4096), dim3(256), 0, stream>>>(yf, l1g + l*D_, l1b + l*D_, attnf, attnb);
    gemm_kernel<<<dim3(128,16), dim3(256), 0, stream>>>(
        attnb, WiT + l*WF, F_, D_, bi + l*F_, (const float*)nullptr, (float*)nullptr, hb, 2);
    gemm_kernel<<<dim3(128,4), dim3(256), 0, stream>>>(
        hb, WfT + l*WF, D_, F_, bfw + l*D_, attnf, yf, (u16*)nullptr, 1);
    ln_kernel<<<dim3(4096), dim3(256), 0, stream>>>(yf, l2g + l*D_, l2b + l*D_, x, xb);
  }
}

// Round 2
// 1511.457 us; speedup vs baseline: 1.1357x; 1.1357x over previous
//
#include <hip/hip_runtime.h>
#include <stdint.h>

// SAINT encoder: B=32 S=512 D=512 H=8 DH=64 F=2048 L=4
#define B_ 32
#define S_ 512
#define D_ 512
#define H_ 8
#define F_ 2048
#define L_ 4
#define DH_ 64
#define M_ (B_*S_)

typedef unsigned short u16;
typedef float f32x4 __attribute__((ext_vector_type(4)));
typedef short bf16x8 __attribute__((ext_vector_type(8)));

__device__ __forceinline__ u16 f2b(float f) {
  unsigned u = __float_as_uint(f);
  u += 0x7FFFu + ((u >> 16) & 1u);
  return (u16)(u >> 16);
}
__device__ __forceinline__ float b2f(u16 u) {
  return __uint_as_float((unsigned)u << 16);
}
__device__ __forceinline__ void gld16(const void* g, void* l) {
  __builtin_amdgcn_global_load_lds((__attribute__((address_space(1))) void*)(void*)g,
                                   (__attribute__((address_space(3))) void*)l, 16, 0, 0);
}
__device__ __forceinline__ f32x4 mfma16(bf16x8 a, bf16x8 b, f32x4 c) {
  return __builtin_amdgcn_mfma_f32_16x16x32_bf16(a, b, c, 0, 0, 0);
}
__device__ __forceinline__ float gelu_exact(float x) {
  return 0.5f * x * (1.0f + erff(x * 0.70710678118654752f));
}

// ---------------- weight transpose + bf16: W[R][C] f32 -> WT[C][R] bf16 -----------
__global__ __launch_bounds__(256) void transpose_w(const float* __restrict__ in,
                                                   u16* __restrict__ out, int R, int C) {
  __shared__ float tile[32][33];
  const int l = blockIdx.z;
  in  += (size_t)l * R * C;
  out += (size_t)l * R * C;
  const int c0 = blockIdx.x * 32, r0 = blockIdx.y * 32;
  const int tx = threadIdx.x, ty = threadIdx.y;
#pragma unroll
  for (int k = 0; k < 4; k++)
    tile[ty + 8*k][tx] = in[(size_t)(r0 + ty + 8*k) * C + c0 + tx];
  __syncthreads();
#pragma unroll
  for (int k = 0; k < 4; k++)
    out[(size_t)(c0 + ty + 8*k) * R + r0 + tx] = f2b(tile[tx][ty + 8*k]);
}

// ---------------- x init ----------------------------------------------------------
__global__ __launch_bounds__(256) void prep_x(const float* __restrict__ h,
                                              float* __restrict__ x, u16* __restrict__ xb) {
  int i = blockIdx.x * 256 + threadIdx.x;
  float4 v = ((const float4*)h)[i];
  ((float4*)x)[i] = v;
  ushort4 u; u.x = f2b(v.x); u.y = f2b(v.y); u.z = f2b(v.z); u.w = f2b(v.w);
  ((ushort4*)xb)[i] = u;
}

// ---------------- invsc precompute: 1/scale as bf16, shared by all layers+heads ---
__global__ __launch_bounds__(256) void prep_invsc(const int* __restrict__ ts,
                                                  u16* __restrict__ out) {
  const int i = blockIdx.x & 511, b = blockIdx.x >> 9;
  const int j = threadIdx.x * 2;
  const float ti = (float)ts[b*S_ + i];
  int2 tj = *(const int2*)(ts + b*S_ + j);
  float lag0 = fmaxf((ti - (float)tj.x) * (1.0f/60000.0f), 0.0f);
  float lag1 = fmaxf((ti - (float)tj.y) * (1.0f/60000.0f), 0.0f);
  // scale = 9 - 1/(lag+1); invsc = (lag+1)/(9*lag+8)
  float v0 = (lag0 + 1.0f) * __builtin_amdgcn_rcpf(fmaf(lag0, 9.0f, 8.0f));
  float v1 = (lag1 + 1.0f) * __builtin_amdgcn_rcpf(fmaf(lag1, 9.0f, 8.0f));
  ushort2 o; o.x = f2b(v0); o.y = f2b(v1);
  *(ushort2*)(out + ((size_t)(b*S_ + i))*S_ + j) = o;
}

// ---------------- pbias f32 -> bf16 -----------------------------------------------
__global__ __launch_bounds__(256) void prep_pb(const float* __restrict__ pb,
                                               u16* __restrict__ out) {
  int i = blockIdx.x * 256 + threadIdx.x;
  float4 v = ((const float4*)pb)[i];
  ushort4 o; o.x = f2b(v.x); o.y = f2b(v.y); o.z = f2b(v.z); o.w = f2b(v.w);
  ((ushort4*)out)[i] = o;
}

// ---------------- GEMM: C[M,N] = A[M,K] * BT[N,K]^T, 128x128 tile, BK=64 ----------
// LDS rows are 64 u16 (128B); chunk c of row r stored at (c ^ (r&7)) -> conflict-free
__device__ __forceinline__ void gemm_core(
    const u16* __restrict__ A, const u16* __restrict__ BT,
    const int N, const int K,
    const float* __restrict__ bias, const float* __restrict__ res,
    float* __restrict__ outf, u16* __restrict__ outb, const int epi)
{
  __shared__ u16 As[128*64];
  __shared__ u16 Bs[128*64];
  const int tid = threadIdx.x;
  const int wid = tid >> 6, lane = tid & 63;
  const int wm = (wid >> 1) * 64, wn = (wid & 1) * 64;
  const int lr = lane & 15, quad = lane >> 4;
  const int m0 = blockIdx.x * 128, n0 = blockIdx.y * 128;
  const int l7 = lane & 7, l3 = lane >> 3;
  const int cc = (l7 ^ l3) * 8;          // swizzled staged col offset (u16)
  const int f8 = lr & 7;                 // read swizzle factor

  f32x4 acc[4][4];
#pragma unroll
  for (int i = 0; i < 4; i++)
#pragma unroll
    for (int j = 0; j < 4; j++) acc[i][j] = (f32x4){0.f, 0.f, 0.f, 0.f};

  const u16* Ag = A  + (size_t)(m0 + wid*16 + l3)*K + cc;
  const u16* Bg = BT + (size_t)(n0 + wid*16 + l3)*K + cc;
  u16* AsW = As + wid*1024;
  u16* BsW = Bs + wid*1024;

  for (int k0 = 0; k0 < K; k0 += 64) {
    gld16(Ag + k0,                 AsW);
    gld16(Ag + (size_t)8*K + k0,   AsW + 512);
    gld16(Ag + (size_t)64*K + k0,  AsW + 4096);
    gld16(Ag + (size_t)72*K + k0,  AsW + 4608);
    gld16(Bg + k0,                 BsW);
    gld16(Bg + (size_t)8*K + k0,   BsW + 512);
    gld16(Bg + (size_t)64*K + k0,  BsW + 4096);
    gld16(Bg + (size_t)72*K + k0,  BsW + 4608);
    __syncthreads();
#pragma unroll
    for (int kh = 0; kh < 2; kh++) {
      bf16x8 af[4], bfr[4];
#pragma unroll
      for (int i = 0; i < 4; i++)
        af[i]  = *(const bf16x8*)(As + (wm + i*16 + lr)*64 + (((kh*4 + quad) ^ f8) * 8));
#pragma unroll
      for (int j = 0; j < 4; j++)
        bfr[j] = *(const bf16x8*)(Bs + (wn + j*16 + lr)*64 + (((kh*4 + quad) ^ f8) * 8));
#pragma unroll
      for (int i = 0; i < 4; i++)
#pragma unroll
        for (int j = 0; j < 4; j++)
          acc[i][j] = mfma16(af[i], bfr[j], acc[i][j]);
    }
    __syncthreads();
  }

#pragma unroll
  for (int j = 0; j < 4; j++) {
    const int n = n0 + wn + j*16 + lr;
    const float bn = bias[n];
#pragma unroll
    for (int i = 0; i < 4; i++) {
      const int mb = m0 + wm + i*16 + quad*4;
#pragma unroll
      for (int r = 0; r < 4; r++) {
        const int m = mb + r;
        float v = acc[i][j][r] + bn;
        if (epi == 0) {
          outb[(size_t)m*N + n] = f2b(v);
        } else if (epi == 1) {
          outf[(size_t)m*N + n] = v + res[(size_t)m*N + n];
        } else if (epi == 2) {
          outb[(size_t)m*N + n] = f2b(gelu_exact(v));
        } else {
          const int bb_ = m >> 9, sr = m & 511, hh = n >> 6, dd = n & 63;
          outb[(((size_t)((bb_*H_ + hh)*DH_ + dd)) << 9) + sr] = f2b(v);
        }
      }
    }
  }
}

__global__ __launch_bounds__(256) void gemm_kernel(
    const u16* A, const u16* BT, int N, int K,
    const float* bias, const float* res, float* outf, u16* outb, int epi)
{
  gemm_core(A, BT, N, K, bias, res, outf, outb, epi);
}

__global__ __launch_bounds__(256) void gemm_qkv_kernel(
    const u16* A, const u16* BTq, size_t zstride, int K,
    const float* b0, const float* b1, const float* b2,
    u16* out0, u16* out1, u16* out2)
{
  const int z = blockIdx.z;
  const u16* BT = BTq + (size_t)z * zstride;
  const float* bias = (z == 0) ? b0 : (z == 1) ? b1 : b2;
  u16* outb = (z == 0) ? out0 : (z == 1) ? out1 : out2;
  gemm_core(A, BT, 512, K, bias, nullptr, nullptr, outb, (z == 2) ? 3 : 0);
}

// ---------------- LayerNorm -------------------------------------------------------
__global__ __launch_bounds__(256) void ln_kernel(
    const float* __restrict__ y, const float* __restrict__ g, const float* __restrict__ bta,
    float* __restrict__ outf, u16* __restrict__ outb)
{
  const int lane = threadIdx.x & 63;
  const int row = blockIdx.x*4 + (threadIdx.x >> 6);
  const float* yr = y + (size_t)row*D_ + lane*8;
  float4 a0 = *(const float4*)yr;
  float4 a1 = *(const float4*)(yr + 4);
  float v[8] = {a0.x, a0.y, a0.z, a0.w, a1.x, a1.y, a1.z, a1.w};
  float s = 0.f;
#pragma unroll
  for (int e = 0; e < 8; e++) s += v[e];
#pragma unroll
  for (int m = 1; m < 64; m <<= 1) s += __shfl_xor(s, m);
  const float mu = s * (1.0f/512.0f);
  float q = 0.f;
#pragma unroll
  for (int e = 0; e < 8; e++) { float d = v[e] - mu; q += d*d; }
#pragma unroll
  for (int m = 1; m < 64; m <<= 1) q += __shfl_xor(q, m);
  const float rs = rsqrtf(q * (1.0f/512.0f) + 1e-12f);
  float4 g0 = *(const float4*)(g + lane*8);
  float4 g1 = *(const float4*)(g + lane*8 + 4);
  float4 b0 = *(const float4*)(bta + lane*8);
  float4 b1 = *(const float4*)(bta + lane*8 + 4);
  float gg[8] = {g0.x, g0.y, g0.z, g0.w, g1.x, g1.y, g1.z, g1.w};
  float bb[8] = {b0.x, b0.y, b0.z, b0.w, b1.x, b1.y, b1.z, b1.w};
  float o[8];
#pragma unroll
  for (int e = 0; e < 8; e++) o[e] = (v[e] - mu) * rs * gg[e] + bb[e];
  float4 w0 = {o[0], o[1], o[2], o[3]}, w1 = {o[4], o[5], o[6], o[7]};
  *(float4*)(outf + (size_t)row*D_ + lane*8)     = w0;
  *(float4*)(outf + (size_t)row*D_ + lane*8 + 4) = w1;
  ushort4 u0 = {f2b(o[0]), f2b(o[1]), f2b(o[2]), f2b(o[3])};
  ushort4 u1 = {f2b(o[4]), f2b(o[5]), f2b(o[6]), f2b(o[7])};
  *(ushort4*)(outb + (size_t)row*D_ + lane*8)     = u0;
  *(ushort4*)(outb + (size_t)row*D_ + lane*8 + 4) = u1;
}

// ---------------- flash attention, no max-subtraction, swizzled LDS ---------------
__global__ __launch_bounds__(256, 4) void attn_kernel(
    const u16* __restrict__ qb, const u16* __restrict__ kb, const u16* __restrict__ vt,
    const u16* __restrict__ pb16, const u16* __restrict__ invsc, u16* __restrict__ cb)
{
  __shared__ u16 QPs[64*64];                 // Q tile; wave's 16-row slice reused as P
  __shared__ u16 Ks[64*64], Vs[64*64], ISs[64*64], PBs[64*64];
  const int it = blockIdx.x, h = blockIdx.y, b = blockIdx.z;
  const int i0 = it * 64;
  const int tid = threadIdx.x, wid = tid >> 6, lane = tid & 63;
  const int lr = lane & 15, quad = lane >> 4;
  const int l7 = lane & 7, l3 = lane >> 3;
  const int cc = (l7 ^ l3) * 8;              // staged swizzle col offset (u16)
  const int f8 = lr & 7;                     // read swizzle factor
  const int rr = wid*8 + l3;

  const u16* qg  = qb + ((size_t)(b*S_ + i0))*D_ + h*DH_;
  const u16* kg  = kb + ((size_t)b*S_)*D_ + h*DH_;
  const u16* vg  = vt + ((size_t)(b*H_ + h)*DH_)*S_;
  const u16* isg = invsc + ((size_t)(b*S_ + i0))*S_;
  const u16* pbg = pb16 + ((size_t)(h*S_ + i0))*S_;

  gld16(qg + (size_t)rr*D_ + cc,        QPs + wid*512);
  gld16(qg + (size_t)(rr+32)*D_ + cc,   QPs + 2048 + wid*512);
  __syncthreads();

  bf16x8 aq0 = *(const bf16x8*)(QPs + (wid*16 + lr)*64 + ((quad ^ f8) * 8));
  bf16x8 aq1 = *(const bf16x8*)(QPs + (wid*16 + lr)*64 + (((quad ^ f8) ^ 4) * 8));
  u16* Pw = QPs + wid*1024;                  // 16x64 P region (aliases this wave's Q rows)

  f32x4 O[4]; float lacc[4];
#pragma unroll
  for (int dt = 0; dt < 4; dt++) O[dt] = (f32x4){0.f, 0.f, 0.f, 0.f};
#pragma unroll
  for (int r = 0; r < 4; r++) lacc[r] = 0.f;
  const int lrh = lr >> 3;

  for (int t8 = 0; t8 < 8; t8++) {
    const int j0 = t8 * 64;
    gld16(kg + (size_t)(j0+rr)*D_ + cc,      Ks + wid*512);
    gld16(kg + (size_t)(j0+rr+32)*D_ + cc,   Ks + 2048 + wid*512);
    gld16(vg + (size_t)rr*S_ + j0 + cc,      Vs + wid*512);
    gld16(vg + (size_t)(rr+32)*S_ + j0 + cc, Vs + 2048 + wid*512);
    gld16(isg + (size_t)rr*S_ + j0 + cc,      ISs + wid*512);
    gld16(isg + (size_t)(rr+32)*S_ + j0 + cc, ISs + 2048 + wid*512);
    gld16(pbg + (size_t)rr*S_ + j0 + cc,      PBs + wid*512);
    gld16(pbg + (size_t)(rr+32)*S_ + j0 + cc, PBs + 2048 + wid*512);
    __syncthreads();

    // S = Q K^T : 16 rows x 64 cols per wave
    f32x4 s[4];
#pragma unroll
    for (int jt = 0; jt < 4; jt++) {
      const u16* kr = Ks + (jt*16 + lr)*64;
      bf16x8 bk0 = *(const bf16x8*)(kr + ((quad ^ f8) * 8));
      bf16x8 bk1 = *(const bf16x8*)(kr + (((quad ^ f8) ^ 4) * 8));
      f32x4 z = (f32x4){0.f, 0.f, 0.f, 0.f};
      z = mfma16(aq0, bk0, z);
      z = mfma16(aq1, bk1, z);
      s[jt] = z;
    }
    // p = exp(qk*invsc + pbias); accumulate row sums; P -> LDS (A-layout)
#pragma unroll
    for (int r = 0; r < 4; r++) {
      const int rowl = quad*4 + r;
      const int rbase = (wid*16 + rowl) * 64;
      const int r7 = rowl & 7;
      float pa = 0.f;
#pragma unroll
      for (int jt = 0; jt < 4; jt++) {
        const int idx = (((jt*2 + lrh) ^ r7) * 8) + l7;
        float isf = b2f(ISs[rbase + idx]);
        float pbf = b2f(PBs[rbase + idx]);
        float p = __expf(fmaf(s[jt][r], isf, pbf));
        pa += p;
        Pw[rowl*64 + idx] = f2b(p);
      }
      lacc[r] += pa;
    }
    // O += P V
    bf16x8 ap0 = *(const bf16x8*)(Pw + lr*64 + ((quad ^ f8) * 8));
    bf16x8 ap1 = *(const bf16x8*)(Pw + lr*64 + (((quad ^ f8) ^ 4) * 8));
#pragma unroll
    for (int dt = 0; dt < 4; dt++) {
      const u16* vr = Vs + (dt*16 + lr)*64;
      bf16x8 bv0 = *(const bf16x8*)(vr + ((quad ^ f8) * 8));
      bf16x8 bv1 = *(const bf16x8*)(vr + (((quad ^ f8) ^ 4) * 8));
      O[dt] = mfma16(ap0, bv0, O[dt]);
      O[dt] = mfma16(ap1, bv1, O[dt]);
    }
    __syncthreads();
  }

#pragma unroll
  for (int r = 0; r < 4; r++) {
    float sum = lacc[r];
#pragma unroll
    for (int m = 1; m < 16; m <<= 1) sum += __shfl_xor(sum, m);
    const float inv = __builtin_amdgcn_rcpf(sum);
    const size_t row = (size_t)(b*S_ + i0 + wid*16 + quad*4 + r);
#pragma unroll
    for (int dt = 0; dt < 4; dt++)
      cb[row*D_ + h*DH_ + dt*16 + lr] = f2b(O[dt][r] * inv);
  }
}

// ---------------- orchestration ---------------------------------------------------
extern "C" void kernel_launch(void* const* d_in, const int* in_sizes, int n_in,
                              void* d_out, int out_size, void* d_ws, size_t ws_size,
                              hipStream_t stream)
{
  const float* hidden = (const float*)d_in[0];
  const float* pbias  = (const float*)d_in[1];
  const int*   ts     = (const int*)d_in[2];
  const float* Wq = (const float*)d_in[3];   const float* bq  = (const float*)d_in[4];
  const float* Wk = (const float*)d_in[5];   const float* bk  = (const float*)d_in[6];
  const float* Wv = (const float*)d_in[7];   const float* bv  = (const float*)d_in[8];
  const float* Wo = (const float*)d_in[9];   const float* bo  = (const float*)d_in[10];
  const float* l1g = (const float*)d_in[11]; const float* l1b = (const float*)d_in[12];
  const float* Wi = (const float*)d_in[13];  const float* bi  = (const float*)d_in[14];
  const float* Wf = (const float*)d_in[15];  const float* bfw = (const float*)d_in[16];
  const float* l2g = (const float*)d_in[17]; const float* l2b = (const float*)d_in[18];

  char* w = (char*)d_ws;
  u16* xb    = (u16*)w; w += (size_t)M_*D_*2;
  u16* qb    = (u16*)w; w += (size_t)M_*D_*2;
  u16* kbuf  = (u16*)w; w += (size_t)M_*D_*2;
  u16* vtw   = (u16*)w; w += (size_t)M_*D_*2;
  u16* cbuf  = (u16*)w; w += (size_t)M_*D_*2;
  u16* attnb = (u16*)w; w += (size_t)M_*D_*2;
  float* yf    = (float*)w; w += (size_t)M_*D_*4;
  float* attnf = (float*)w; w += (size_t)M_*D_*4;
  u16* WqkvT = (u16*)w; w += (size_t)3*L_*D_*D_*2;
  u16* WoT   = (u16*)w; w += (size_t)L_*D_*D_*2;
  u16* WiT   = (u16*)w; w += (size_t)L_*D_*F_*2;
  u16* WfT   = (u16*)w; w += (size_t)L_*F_*D_*2;
  u16* invsc = (u16*)w; w += (size_t)B_*S_*S_*2;
  u16* pbb   = (u16*)w; w += (size_t)H_*S_*S_*2;
  u16* hb    = qb;   // alias: qb..cbuf = M_*F_ bf16; lifetimes disjoint

  float* x = (float*)d_out;

  const size_t WD = (size_t)D_*D_;
  const size_t WF = (size_t)D_*F_;
  dim3 tb(32, 8);

  transpose_w<<<dim3(16,16,L_), tb, 0, stream>>>(Wq, WqkvT,           D_, D_);
  transpose_w<<<dim3(16,16,L_), tb, 0, stream>>>(Wk, WqkvT + L_*WD,   D_, D_);
  transpose_w<<<dim3(16,16,L_), tb, 0, stream>>>(Wv, WqkvT + 2*L_*WD, D_, D_);
  transpose_w<<<dim3(16,16,L_), tb, 0, stream>>>(Wo, WoT,             D_, D_);
  transpose_w<<<dim3(64,16,L_), tb, 0, stream>>>(Wi, WiT,             D_, F_);
  transpose_w<<<dim3(16,64,L_), tb, 0, stream>>>(Wf, WfT,             F_, D_);
  prep_x<<<dim3(8192), dim3(256), 0, stream>>>(hidden, x, xb);
  prep_invsc<<<dim3(B_*S_), dim3(256), 0, stream>>>(ts, invsc);
  prep_pb<<<dim3(H_*S_*S_/1024), dim3(256), 0, stream>>>(pbias, pbb);

  for (int l = 0; l < L_; l++) {
    gemm_qkv_kernel<<<dim3(128,4,3), dim3(256), 0, stream>>>(
        xb, WqkvT + l*WD, (size_t)L_*WD, D_,
        bq + l*D_, bk + l*D_, bv + l*D_, qb, kbuf, vtw);
    attn_kernel<<<dim3(8,H_,B_), dim3(256), 0, stream>>>(qb, kbuf, vtw, pbb, invsc, cbuf);
    gemm_kernel<<<dim3(128,4), dim3(256), 0, stream>>>(
        cbuf, WoT + l*WD, D_, D_, bo + l*D_, x, yf, (u16*)nullptr, 1);
    ln_kernel<<<dim3(4096), dim3(256), 0, stream>>>(yf, l1g + l*D_, l1b + l*D_, attnf, attnb);
    gemm_kernel<<<dim3(128,16), dim3(256), 0, stream>>>(
        attnb, WiT + l*WF, F_, D_, bi + l*F_, (const float*)nullptr, (float*)nullptr, hb, 2);
    gemm_kernel<<<dim3(128,4), dim3(256), 0, stream>>>(
        hb, WfT + l*WF, D_, F_, bfw + l*D_, attnf, yf, (u16*)nullptr, 1);
    ln_kernel<<<dim3(4096), dim3(256), 0, stream>>>(yf, l2g + l*D_, l2b + l*D_, x, xb);
  }
}

// Round 3
// 1244.268 us; speedup vs baseline: 1.3796x; 1.2147x over previous
//
#include <hip/hip_runtime.h>
#include <stdint.h>

// SAINT encoder: B=32 S=512 D=512 H=8 DH=64 F=2048 L=4
#define B_ 32
#define S_ 512
#define D_ 512
#define H_ 8
#define F_ 2048
#define L_ 4
#define DH_ 64
#define M_ (B_*S_)

typedef unsigned short u16;
typedef float f32x4 __attribute__((ext_vector_type(4)));
typedef short bf16x8 __attribute__((ext_vector_type(8)));

__device__ __forceinline__ u16 f2b(float f) {
  unsigned u = __float_as_uint(f);
  u += 0x7FFFu + ((u >> 16) & 1u);
  return (u16)(u >> 16);
}
__device__ __forceinline__ float b2f(u16 u) {
  return __uint_as_float((unsigned)u << 16);
}
__device__ __forceinline__ void gld16(const void* g, void* l) {
  __builtin_amdgcn_global_load_lds((__attribute__((address_space(1))) void*)(void*)g,
                                   (__attribute__((address_space(3))) void*)l, 16, 0, 0);
}
__device__ __forceinline__ f32x4 mfma16(bf16x8 a, bf16x8 b, f32x4 c) {
  return __builtin_amdgcn_mfma_f32_16x16x32_bf16(a, b, c, 0, 0, 0);
}
__device__ __forceinline__ float gelu_exact(float x) {
  return 0.5f * x * (1.0f + erff(x * 0.70710678118654752f));
}

// ---------------- weight transpose + bf16: W[R][C] f32 -> WT[C][R] bf16 -----------
__global__ __launch_bounds__(256) void transpose_w(const float* __restrict__ in,
                                                   u16* __restrict__ out, int R, int C) {
  __shared__ float tile[32][33];
  const int l = blockIdx.z;
  in  += (size_t)l * R * C;
  out += (size_t)l * R * C;
  const int c0 = blockIdx.x * 32, r0 = blockIdx.y * 32;
  const int tx = threadIdx.x, ty = threadIdx.y;
#pragma unroll
  for (int k = 0; k < 4; k++)
    tile[ty + 8*k][tx] = in[(size_t)(r0 + ty + 8*k) * C + c0 + tx];
  __syncthreads();
#pragma unroll
  for (int k = 0; k < 4; k++)
    out[(size_t)(c0 + ty + 8*k) * R + r0 + tx] = f2b(tile[tx][ty + 8*k]);
}

// ---------------- x init ----------------------------------------------------------
__global__ __launch_bounds__(256) void prep_x(const float* __restrict__ h,
                                              float* __restrict__ x, u16* __restrict__ xb) {
  int i = blockIdx.x * 256 + threadIdx.x;
  float4 v = ((const float4*)h)[i];
  ((float4*)x)[i] = v;
  ushort4 u; u.x = f2b(v.x); u.y = f2b(v.y); u.z = f2b(v.z); u.w = f2b(v.w);
  ((ushort4*)xb)[i] = u;
}

// ---------------- invsc precompute: 1/scale as bf16 -------------------------------
__global__ __launch_bounds__(256) void prep_invsc(const int* __restrict__ ts,
                                                  u16* __restrict__ out) {
  const int i = blockIdx.x & 511, b = blockIdx.x >> 9;
  const int j = threadIdx.x * 2;
  const float ti = (float)ts[b*S_ + i];
  int2 tj = *(const int2*)(ts + b*S_ + j);
  float lag0 = fmaxf((ti - (float)tj.x) * (1.0f/60000.0f), 0.0f);
  float lag1 = fmaxf((ti - (float)tj.y) * (1.0f/60000.0f), 0.0f);
  float v0 = (lag0 + 1.0f) * __builtin_amdgcn_rcpf(fmaf(lag0, 9.0f, 8.0f));
  float v1 = (lag1 + 1.0f) * __builtin_amdgcn_rcpf(fmaf(lag1, 9.0f, 8.0f));
  ushort2 o; o.x = f2b(v0); o.y = f2b(v1);
  *(ushort2*)(out + ((size_t)(b*S_ + i))*S_ + j) = o;
}

// ---------------- pbias f32 -> bf16 -----------------------------------------------
__global__ __launch_bounds__(256) void prep_pb(const float* __restrict__ pb,
                                               u16* __restrict__ out) {
  int i = blockIdx.x * 256 + threadIdx.x;
  float4 v = ((const float4*)pb)[i];
  ushort4 o; o.x = f2b(v.x); o.y = f2b(v.y); o.z = f2b(v.z); o.w = f2b(v.w);
  ((ushort4*)out)[i] = o;
}

// ---------------- GEMM: C[M,N] = A[M,K] * BT[N,K]^T, 128x128 tile, BK=64 ----------
// epi: 0 = bf16 (+bias); 1 = bf16 (+bias + bf16 residual); 2 = bf16 gelu(+bias);
//      3 = bf16 transposed V layout [B,H,DH,S] (+bias), r-packed ushort4 stores
__device__ __forceinline__ void gemm_core(
    const u16* __restrict__ A, const u16* __restrict__ BT,
    const int N, const int K,
    const float* __restrict__ bias, const u16* __restrict__ res,
    u16* __restrict__ outb, const int epi)
{
  __shared__ u16 As[128*64];
  __shared__ u16 Bs[128*64];
  const int tid = threadIdx.x;
  const int wid = tid >> 6, lane = tid & 63;
  const int wm = (wid >> 1) * 64, wn = (wid & 1) * 64;
  const int lr = lane & 15, quad = lane >> 4;
  const int m0 = blockIdx.x * 128, n0 = blockIdx.y * 128;
  const int l7 = lane & 7, l3 = lane >> 3;
  const int cc = (l7 ^ l3) * 8;          // swizzled staged col offset (u16)
  const int f8 = lr & 7;                 // read swizzle factor

  f32x4 acc[4][4];
#pragma unroll
  for (int i = 0; i < 4; i++)
#pragma unroll
    for (int j = 0; j < 4; j++) acc[i][j] = (f32x4){0.f, 0.f, 0.f, 0.f};

  const u16* Ag = A  + (size_t)(m0 + wid*16 + l3)*K + cc;
  const u16* Bg = BT + (size_t)(n0 + wid*16 + l3)*K + cc;
  u16* AsW = As + wid*1024;
  u16* BsW = Bs + wid*1024;

  for (int k0 = 0; k0 < K; k0 += 64) {
    gld16(Ag + k0,                 AsW);
    gld16(Ag + (size_t)8*K + k0,   AsW + 512);
    gld16(Ag + (size_t)64*K + k0,  AsW + 4096);
    gld16(Ag + (size_t)72*K + k0,  AsW + 4608);
    gld16(Bg + k0,                 BsW);
    gld16(Bg + (size_t)8*K + k0,   BsW + 512);
    gld16(Bg + (size_t)64*K + k0,  BsW + 4096);
    gld16(Bg + (size_t)72*K + k0,  BsW + 4608);
    __syncthreads();
#pragma unroll
    for (int kh = 0; kh < 2; kh++) {
      bf16x8 af[4], bfr[4];
#pragma unroll
      for (int i = 0; i < 4; i++)
        af[i]  = *(const bf16x8*)(As + (wm + i*16 + lr)*64 + (((kh*4 + quad) ^ f8) * 8));
#pragma unroll
      for (int j = 0; j < 4; j++)
        bfr[j] = *(const bf16x8*)(Bs + (wn + j*16 + lr)*64 + (((kh*4 + quad) ^ f8) * 8));
#pragma unroll
      for (int i = 0; i < 4; i++)
#pragma unroll
        for (int j = 0; j < 4; j++)
          acc[i][j] = mfma16(af[i], bfr[j], acc[i][j]);
    }
    __syncthreads();
  }

  // bias for this lane's 4 j-columns
  float bn[4];
#pragma unroll
  for (int j = 0; j < 4; j++) bn[j] = bias[n0 + wn + j*16 + lr];

  if (epi == 3) {
#pragma unroll
    for (int i = 0; i < 4; i++) {
      const int m = m0 + wm + i*16 + quad*4;     // sr base; r spans +0..3
      const int bb_ = m >> 9, sr = m & 511;
#pragma unroll
      for (int j = 0; j < 4; j++) {
        const int n = n0 + wn + j*16 + lr;
        const int hh = n >> 6, dd = n & 63;
        ushort4 o;
        o.x = f2b(acc[i][j][0] + bn[j]);
        o.y = f2b(acc[i][j][1] + bn[j]);
        o.z = f2b(acc[i][j][2] + bn[j]);
        o.w = f2b(acc[i][j][3] + bn[j]);
        *(ushort4*)(outb + (((size_t)((bb_*H_ + hh)*DH_ + dd)) << 9) + sr) = o;
      }
    }
  } else {
#pragma unroll
    for (int i = 0; i < 4; i++) {
#pragma unroll
      for (int r = 0; r < 4; r++) {
        const size_t m = (size_t)(m0 + wm + i*16 + quad*4 + r);
#pragma unroll
        for (int j = 0; j < 4; j++) {           // j innermost: 4 adjacent 32B stores/row
          const int n = n0 + wn + j*16 + lr;
          float v = acc[i][j][r] + bn[j];
          if (epi == 0)      outb[m*N + n] = f2b(v);
          else if (epi == 1) outb[m*N + n] = f2b(v + b2f(res[m*N + n]));
          else               outb[m*N + n] = f2b(gelu_exact(v));
        }
      }
    }
  }
}

__global__ __launch_bounds__(256) void gemm_kernel(
    const u16* A, const u16* BT, int N, int K,
    const float* bias, const u16* res, u16* outb, int epi)
{
  gemm_core(A, BT, N, K, bias, res, outb, epi);
}

__global__ __launch_bounds__(256) void gemm_qkv_kernel(
    const u16* A, const u16* BTq, size_t zstride, int K,
    const float* b0, const float* b1, const float* b2,
    u16* out0, u16* out1, u16* out2)
{
  const int z = blockIdx.z;
  const u16* BT = BTq + (size_t)z * zstride;
  const float* bias = (z == 0) ? b0 : (z == 1) ? b1 : b2;
  u16* outb = (z == 0) ? out0 : (z == 1) ? out1 : out2;
  gemm_core(A, BT, 512, K, bias, nullptr, outb, (z == 2) ? 3 : 0);
}

// ---------------- LayerNorm: bf16 in; bf16 out + optional f32 out -----------------
__global__ __launch_bounds__(256) void ln_kernel(
    const u16* __restrict__ y, const float* __restrict__ g, const float* __restrict__ bta,
    float* __restrict__ outf, u16* __restrict__ outb)
{
  const int lane = threadIdx.x & 63;
  const int row = blockIdx.x*4 + (threadIdx.x >> 6);
  const u16* yr = y + (size_t)row*D_ + lane*8;
  ushort4 a0 = *(const ushort4*)yr;
  ushort4 a1 = *(const ushort4*)(yr + 4);
  float v[8] = {b2f(a0.x), b2f(a0.y), b2f(a0.z), b2f(a0.w),
                b2f(a1.x), b2f(a1.y), b2f(a1.z), b2f(a1.w)};
  float s = 0.f;
#pragma unroll
  for (int e = 0; e < 8; e++) s += v[e];
#pragma unroll
  for (int m = 1; m < 64; m <<= 1) s += __shfl_xor(s, m);
  const float mu = s * (1.0f/512.0f);
  float q = 0.f;
#pragma unroll
  for (int e = 0; e < 8; e++) { float d = v[e] - mu; q += d*d; }
#pragma unroll
  for (int m = 1; m < 64; m <<= 1) q += __shfl_xor(q, m);
  const float rs = rsqrtf(q * (1.0f/512.0f) + 1e-12f);
  float4 g0 = *(const float4*)(g + lane*8);
  float4 g1 = *(const float4*)(g + lane*8 + 4);
  float4 b0 = *(const float4*)(bta + lane*8);
  float4 b1 = *(const float4*)(bta + lane*8 + 4);
  float gg[8] = {g0.x, g0.y, g0.z, g0.w, g1.x, g1.y, g1.z, g1.w};
  float bb[8] = {b0.x, b0.y, b0.z, b0.w, b1.x, b1.y, b1.z, b1.w};
  float o[8];
#pragma unroll
  for (int e = 0; e < 8; e++) o[e] = (v[e] - mu) * rs * gg[e] + bb[e];
  if (outf) {
    float4 w0 = {o[0], o[1], o[2], o[3]}, w1 = {o[4], o[5], o[6], o[7]};
    *(float4*)(outf + (size_t)row*D_ + lane*8)     = w0;
    *(float4*)(outf + (size_t)row*D_ + lane*8 + 4) = w1;
  }
  ushort4 u0 = {f2b(o[0]), f2b(o[1]), f2b(o[2]), f2b(o[3])};
  ushort4 u1 = {f2b(o[4]), f2b(o[5]), f2b(o[6]), f2b(o[7])};
  *(ushort4*)(outb + (size_t)row*D_ + lane*8)     = u0;
  *(ushort4*)(outb + (size_t)row*D_ + lane*8 + 4) = u1;
}

// ---------------- flash attention, no max-subtraction, swizzled LDS ---------------
__global__ __launch_bounds__(256, 4) void attn_kernel(
    const u16* __restrict__ qb, const u16* __restrict__ kb, const u16* __restrict__ vt,
    const u16* __restrict__ pb16, const u16* __restrict__ invsc, u16* __restrict__ cb)
{
  __shared__ u16 QPs[64*64];                 // Q tile; wave's 16-row slice reused as P
  __shared__ u16 Ks[64*64], Vs[64*64], ISs[64*64], PBs[64*64];
  const int it = blockIdx.x, h = blockIdx.y, b = blockIdx.z;
  const int i0 = it * 64;
  const int tid = threadIdx.x, wid = tid >> 6, lane = tid & 63;
  const int lr = lane & 15, quad = lane >> 4;
  const int l7 = lane & 7, l3 = lane >> 3;
  const int cc = (l7 ^ l3) * 8;
  const int f8 = lr & 7;
  const int rr = wid*8 + l3;

  const u16* qg  = qb + ((size_t)(b*S_ + i0))*D_ + h*DH_;
  const u16* kg  = kb + ((size_t)b*S_)*D_ + h*DH_;
  const u16* vg  = vt + ((size_t)(b*H_ + h)*DH_)*S_;
  const u16* isg = invsc + ((size_t)(b*S_ + i0))*S_;
  const u16* pbg = pb16 + ((size_t)(h*S_ + i0))*S_;

  gld16(qg + (size_t)rr*D_ + cc,        QPs + wid*512);
  gld16(qg + (size_t)(rr+32)*D_ + cc,   QPs + 2048 + wid*512);
  __syncthreads();

  bf16x8 aq0 = *(const bf16x8*)(QPs + (wid*16 + lr)*64 + ((quad ^ f8) * 8));
  bf16x8 aq1 = *(const bf16x8*)(QPs + (wid*16 + lr)*64 + (((quad ^ f8) ^ 4) * 8));
  u16* Pw = QPs + wid*1024;

  f32x4 O[4]; float lacc[4];
#pragma unroll
  for (int dt = 0; dt < 4; dt++) O[dt] = (f32x4){0.f, 0.f, 0.f, 0.f};
#pragma unroll
  for (int r = 0; r < 4; r++) lacc[r] = 0.f;
  const int lrh = lr >> 3;

  for (int t8 = 0; t8 < 8; t8++) {
    const int j0 = t8 * 64;
    gld16(kg + (size_t)(j0+rr)*D_ + cc,      Ks + wid*512);
    gld16(kg + (size_t)(j0+rr+32)*D_ + cc,   Ks + 2048 + wid*512);
    gld16(vg + (size_t)rr*S_ + j0 + cc,      Vs + wid*512);
    gld16(vg + (size_t)(rr+32)*S_ + j0 + cc, Vs + 2048 + wid*512);
    gld16(isg + (size_t)rr*S_ + j0 + cc,      ISs + wid*512);
    gld16(isg + (size_t)(rr+32)*S_ + j0 + cc, ISs + 2048 + wid*512);
    gld16(pbg + (size_t)rr*S_ + j0 + cc,      PBs + wid*512);
    gld16(pbg + (size_t)(rr+32)*S_ + j0 + cc, PBs + 2048 + wid*512);
    __syncthreads();

    f32x4 s[4];
#pragma unroll
    for (int jt = 0; jt < 4; jt++) {
      const u16* kr = Ks + (jt*16 + lr)*64;
      bf16x8 bk0 = *(const bf16x8*)(kr + ((quad ^ f8) * 8));
      bf16x8 bk1 = *(const bf16x8*)(kr + (((quad ^ f8) ^ 4) * 8));
      f32x4 z = (f32x4){0.f, 0.f, 0.f, 0.f};
      z = mfma16(aq0, bk0, z);
      z = mfma16(aq1, bk1, z);
      s[jt] = z;
    }
#pragma unroll
    for (int r = 0; r < 4; r++) {
      const int rowl = quad*4 + r;
      const int rbase = (wid*16 + rowl) * 64;
      const int r7 = rowl & 7;
      float pa = 0.f;
#pragma unroll
      for (int jt = 0; jt < 4; jt++) {
        const int idx = (((jt*2 + lrh) ^ r7) * 8) + l7;
        float isf = b2f(ISs[rbase + idx]);
        float pbf = b2f(PBs[rbase + idx]);
        float p = __expf(fmaf(s[jt][r], isf, pbf));
        pa += p;
        Pw[rowl*64 + idx] = f2b(p);
      }
      lacc[r] += pa;
    }
    bf16x8 ap0 = *(const bf16x8*)(Pw + lr*64 + ((quad ^ f8) * 8));
    bf16x8 ap1 = *(const bf16x8*)(Pw + lr*64 + (((quad ^ f8) ^ 4) * 8));
#pragma unroll
    for (int dt = 0; dt < 4; dt++) {
      const u16* vr = Vs + (dt*16 + lr)*64;
      bf16x8 bv0 = *(const bf16x8*)(vr + ((quad ^ f8) * 8));
      bf16x8 bv1 = *(const bf16x8*)(vr + (((quad ^ f8) ^ 4) * 8));
      O[dt] = mfma16(ap0, bv0, O[dt]);
      O[dt] = mfma16(ap1, bv1, O[dt]);
    }
    __syncthreads();
  }

#pragma unroll
  for (int r = 0; r < 4; r++) {
    float sum = lacc[r];
#pragma unroll
    for (int m = 1; m < 16; m <<= 1) sum += __shfl_xor(sum, m);
    const float inv = __builtin_amdgcn_rcpf(sum);
    const size_t row = (size_t)(b*S_ + i0 + wid*16 + quad*4 + r);
#pragma unroll
    for (int dt = 0; dt < 4; dt++)
      cb[row*D_ + h*DH_ + dt*16 + lr] = f2b(O[dt][r] * inv);
  }
}

// ---------------- orchestration ---------------------------------------------------
extern "C" void kernel_launch(void* const* d_in, const int* in_sizes, int n_in,
                              void* d_out, int out_size, void* d_ws, size_t ws_size,
                              hipStream_t stream)
{
  const float* hidden = (const float*)d_in[0];
  const float* pbias  = (const float*)d_in[1];
  const int*   ts     = (const int*)d_in[2];
  const float* Wq = (const float*)d_in[3];   const float* bq  = (const float*)d_in[4];
  const float* Wk = (const float*)d_in[5];   const float* bk  = (const float*)d_in[6];
  const float* Wv = (const float*)d_in[7];   const float* bv  = (const float*)d_in[8];
  const float* Wo = (const float*)d_in[9];   const float* bo  = (const float*)d_in[10];
  const float* l1g = (const float*)d_in[11]; const float* l1b = (const float*)d_in[12];
  const float* Wi = (const float*)d_in[13];  const float* bi  = (const float*)d_in[14];
  const float* Wf = (const float*)d_in[15];  const float* bfw = (const float*)d_in[16];
  const float* l2g = (const float*)d_in[17]; const float* l2b = (const float*)d_in[18];

  char* w = (char*)d_ws;
  u16* xb    = (u16*)w; w += (size_t)M_*D_*2;
  u16* qb    = (u16*)w; w += (size_t)M_*D_*2;
  u16* kbuf  = (u16*)w; w += (size_t)M_*D_*2;
  u16* vtw   = (u16*)w; w += (size_t)M_*D_*2;
  u16* cbuf  = (u16*)w; w += (size_t)M_*D_*2;
  u16* attnb = (u16*)w; w += (size_t)M_*D_*2;
  u16* yb    = (u16*)w; w += (size_t)M_*D_*2;
  u16* WqkvT = (u16*)w; w += (size_t)3*L_*D_*D_*2;
  u16* WoT   = (u16*)w; w += (size_t)L_*D_*D_*2;
  u16* WiT   = (u16*)w; w += (size_t)L_*D_*F_*2;
  u16* WfT   = (u16*)w; w += (size_t)L_*F_*D_*2;
  u16* invsc = (u16*)w; w += (size_t)B_*S_*S_*2;
  u16* pbb   = (u16*)w; w += (size_t)H_*S_*S_*2;
  u16* hb    = qb;   // alias: qb..cbuf = M_*F_ bf16; lifetimes disjoint

  float* x = (float*)d_out;

  const size_t WD = (size_t)D_*D_;
  const size_t WF = (size_t)D_*F_;
  dim3 tb(32, 8);

  transpose_w<<<dim3(16,16,L_), tb, 0, stream>>>(Wq, WqkvT,           D_, D_);
  transpose_w<<<dim3(16,16,L_), tb, 0, stream>>>(Wk, WqkvT + L_*WD,   D_, D_);
  transpose_w<<<dim3(16,16,L_), tb, 0, stream>>>(Wv, WqkvT + 2*L_*WD, D_, D_);
  transpose_w<<<dim3(16,16,L_), tb, 0, stream>>>(Wo, WoT,             D_, D_);
  transpose_w<<<dim3(64,16,L_), tb, 0, stream>>>(Wi, WiT,             D_, F_);
  transpose_w<<<dim3(16,64,L_), tb, 0, stream>>>(Wf, WfT,             F_, D_);
  prep_x<<<dim3(8192), dim3(256), 0, stream>>>(hidden, x, xb);
  prep_invsc<<<dim3(B_*S_), dim3(256), 0, stream>>>(ts, invsc);
  prep_pb<<<dim3(H_*S_*S_/1024), dim3(256), 0, stream>>>(pbias, pbb);

  for (int l = 0; l < L_; l++) {
    gemm_qkv_kernel<<<dim3(128,4,3), dim3(256), 0, stream>>>(
        xb, WqkvT + l*WD, (size_t)L_*WD, D_,
        bq + l*D_, bk + l*D_, bv + l*D_, qb, kbuf, vtw);
    attn_kernel<<<dim3(8,H_,B_), dim3(256), 0, stream>>>(qb, kbuf, vtw, pbb, invsc, cbuf);
    gemm_kernel<<<dim3(128,4), dim3(256), 0, stream>>>(
        cbuf, WoT + l*WD, D_, D_, bo + l*D_, xb, yb, 1);
    ln_kernel<<<dim3(4096), dim3(256), 0, stream>>>(yb, l1g + l*D_, l1b + l*D_,
                                                    (float*)nullptr, attnb);
    gemm_kernel<<<dim3(128,16), dim3(256), 0, stream>>>(
        attnb, WiT + l*WF, F_, D_, bi + l*F_, (const u16*)nullptr, hb, 2);
    gemm_kernel<<<dim3(128,4), dim3(256), 0, stream>>>(
        hb, WfT + l*WF, D_, F_, bfw + l*D_, attnb, yb, 1);
    ln_kernel<<<dim3(4096), dim3(256), 0, stream>>>(yb, l2g + l*D_, l2b + l*D_, x, xb);
  }
}

// Round 4
// 1220.016 us; speedup vs baseline: 1.4070x; 1.0199x over previous
//
#include <hip/hip_runtime.h>
#include <stdint.h>

// SAINT encoder: B=32 S=512 D=512 H=8 DH=64 F=2048 L=4
#define B_ 32
#define S_ 512
#define D_ 512
#define H_ 8
#define F_ 2048
#define L_ 4
#define DH_ 64
#define M_ (B_*S_)

typedef unsigned short u16;
typedef float f32x4 __attribute__((ext_vector_type(4)));
typedef short bf16x8 __attribute__((ext_vector_type(8)));

__device__ __forceinline__ u16 f2b(float f) {
  unsigned u = __float_as_uint(f);
  u += 0x7FFFu + ((u >> 16) & 1u);
  return (u16)(u >> 16);
}
__device__ __forceinline__ float b2f(u16 u) {
  return __uint_as_float((unsigned)u << 16);
}
__device__ __forceinline__ void gld16(const void* g, void* l) {
  __builtin_amdgcn_global_load_lds((__attribute__((address_space(1))) void*)(void*)g,
                                   (__attribute__((address_space(3))) void*)l, 16, 0, 0);
}
__device__ __forceinline__ f32x4 mfma16(bf16x8 a, bf16x8 b, f32x4 c) {
  return __builtin_amdgcn_mfma_f32_16x16x32_bf16(a, b, c, 0, 0, 0);
}
__device__ __forceinline__ float gelu_exact(float x) {
  return 0.5f * x * (1.0f + erff(x * 0.70710678118654752f));
}
// B-permutation: LDS row p <-> global col offset (within 128-col tile)
__device__ __forceinline__ int nmap(int p) {
  return ((p >> 6) << 6) + ((p & 15) << 2) + ((p & 63) >> 4);
}

// ---------------- weight transpose + bf16: W[R][C] f32 -> WT[C][R] bf16 -----------
__global__ __launch_bounds__(256) void transpose_w(const float* __restrict__ in,
                                                   u16* __restrict__ out, int R, int C) {
  __shared__ float tile[32][33];
  const int l = blockIdx.z;
  in  += (size_t)l * R * C;
  out += (size_t)l * R * C;
  const int c0 = blockIdx.x * 32, r0 = blockIdx.y * 32;
  const int tx = threadIdx.x, ty = threadIdx.y;
#pragma unroll
  for (int k = 0; k < 4; k++)
    tile[ty + 8*k][tx] = in[(size_t)(r0 + ty + 8*k) * C + c0 + tx];
  __syncthreads();
#pragma unroll
  for (int k = 0; k < 4; k++)
    out[(size_t)(c0 + ty + 8*k) * R + r0 + tx] = f2b(tile[tx][ty + 8*k]);
}

// ---------------- x init ----------------------------------------------------------
__global__ __launch_bounds__(256) void prep_x(const float* __restrict__ h,
                                              float* __restrict__ x, u16* __restrict__ xb) {
  int i = blockIdx.x * 256 + threadIdx.x;
  float4 v = ((const float4*)h)[i];
  ((float4*)x)[i] = v;
  ushort4 u; u.x = f2b(v.x); u.y = f2b(v.y); u.z = f2b(v.z); u.w = f2b(v.w);
  ((ushort4*)xb)[i] = u;
}

// ---------------- pbias f32 -> bf16 -----------------------------------------------
__global__ __launch_bounds__(256) void prep_pb(const float* __restrict__ pb,
                                               u16* __restrict__ out) {
  int i = blockIdx.x * 256 + threadIdx.x;
  float4 v = ((const float4*)pb)[i];
  ushort4 o; o.x = f2b(v.x); o.y = f2b(v.y); o.z = f2b(v.z); o.w = f2b(v.w);
  ((ushort4*)out)[i] = o;
}

// ---------------- GEMM: C[M,N] = A[M,K] * BT[N,K]^T, 128x128 tile, BK=64 ----------
// B staged with n-permutation so lane lr's 4 j-tiles are 4 consecutive cols.
// epi: 0 = bf16 (+bias); 1 = bf16 (+bias + f32 residual); 2 = bf16 gelu(+bias);
//      3 = bf16 transposed V layout [B,H,DH,S] (+bias)
__device__ __forceinline__ void gemm_core(
    const u16* __restrict__ A, const u16* __restrict__ BT,
    const int N, const int K,
    const float* __restrict__ bias, const float* __restrict__ resf,
    u16* __restrict__ outb, const int epi)
{
  __shared__ u16 As[128*64];
  __shared__ u16 Bs[128*64];
  const int tid = threadIdx.x;
  const int wid = tid >> 6, lane = tid & 63;
  const int wm = (wid >> 1) * 64, wn = (wid & 1) * 64;
  const int lr = lane & 15, quad = lane >> 4;
  const int m0 = blockIdx.x * 128, n0 = blockIdx.y * 128;
  const int l7 = lane & 7, l3 = lane >> 3;
  const int cc = (l7 ^ l3) * 8;          // swizzled staged col offset (u16)
  const int f8 = lr & 7;                 // read swizzle factor

  f32x4 acc[4][4];
#pragma unroll
  for (int i = 0; i < 4; i++)
#pragma unroll
    for (int j = 0; j < 4; j++) acc[i][j] = (f32x4){0.f, 0.f, 0.f, 0.f};

  const u16* Ag = A + (size_t)(m0 + wid*16 + l3)*K + cc;
  const int pbase = wid*16 + l3;
  const u16* Bg0 = BT + (size_t)(n0 + nmap(pbase))*K + cc;
  const u16* Bg1 = BT + (size_t)(n0 + nmap(pbase + 8))*K + cc;
  const u16* Bg2 = BT + (size_t)(n0 + nmap(pbase + 64))*K + cc;
  const u16* Bg3 = BT + (size_t)(n0 + nmap(pbase + 72))*K + cc;
  u16* AsW = As + wid*1024;
  u16* BsW = Bs + wid*1024;

  for (int k0 = 0; k0 < K; k0 += 64) {
    gld16(Ag + k0,                 AsW);
    gld16(Ag + (size_t)8*K + k0,   AsW + 512);
    gld16(Ag + (size_t)64*K + k0,  AsW + 4096);
    gld16(Ag + (size_t)72*K + k0,  AsW + 4608);
    gld16(Bg0 + k0, BsW);
    gld16(Bg1 + k0, BsW + 512);
    gld16(Bg2 + k0, BsW + 4096);
    gld16(Bg3 + k0, BsW + 4608);
    __syncthreads();
#pragma unroll
    for (int kh = 0; kh < 2; kh++) {
      bf16x8 af[4], bfr[4];
#pragma unroll
      for (int i = 0; i < 4; i++)
        af[i]  = *(const bf16x8*)(As + (wm + i*16 + lr)*64 + (((kh*4 + quad) ^ f8) * 8));
#pragma unroll
      for (int j = 0; j < 4; j++)
        bfr[j] = *(const bf16x8*)(Bs + (wn + j*16 + lr)*64 + (((kh*4 + quad) ^ f8) * 8));
#pragma unroll
      for (int i = 0; i < 4; i++)
#pragma unroll
        for (int j = 0; j < 4; j++)
          acc[i][j] = mfma16(af[i], bfr[j], acc[i][j]);
    }
    __syncthreads();
  }

  // lane lr's 4 consecutive cols: colb..colb+3 (tile jt -> colb+jt)
  const int colb = n0 + wn + lr*4;
  const float4 bn4 = *(const float4*)(bias + colb);
  const float bn[4] = {bn4.x, bn4.y, bn4.z, bn4.w};

  if (epi == 3) {
#pragma unroll
    for (int i = 0; i < 4; i++) {
      const int m = m0 + wm + i*16 + quad*4;     // sr base; r spans +0..3
      const int bb_ = m >> 9, sr = m & 511;
#pragma unroll
      for (int j = 0; j < 4; j++) {
        const int n = colb + j;
        const int hh = n >> 6, dd = n & 63;
        ushort4 o;
        o.x = f2b(acc[i][j][0] + bn[j]);
        o.y = f2b(acc[i][j][1] + bn[j]);
        o.z = f2b(acc[i][j][2] + bn[j]);
        o.w = f2b(acc[i][j][3] + bn[j]);
        *(ushort4*)(outb + (((size_t)((bb_*H_ + hh)*DH_ + dd)) << 9) + sr) = o;
      }
    }
  } else {
#pragma unroll
    for (int i = 0; i < 4; i++) {
#pragma unroll
      for (int r = 0; r < 4; r++) {
        const size_t m = (size_t)(m0 + wm + i*16 + quad*4 + r);
        float v[4];
#pragma unroll
        for (int j = 0; j < 4; j++) v[j] = acc[i][j][r] + bn[j];
        if (epi == 1) {
          const float4 rv = *(const float4*)(resf + m*N + colb);
          v[0] += rv.x; v[1] += rv.y; v[2] += rv.z; v[3] += rv.w;
        } else if (epi == 2) {
#pragma unroll
          for (int j = 0; j < 4; j++) v[j] = gelu_exact(v[j]);
        }
        ushort4 o; o.x = f2b(v[0]); o.y = f2b(v[1]); o.z = f2b(v[2]); o.w = f2b(v[3]);
        *(ushort4*)(outb + m*N + colb) = o;
      }
    }
  }
}

__global__ __launch_bounds__(256) void gemm_kernel(
    const u16* A, const u16* BT, int N, int K,
    const float* bias, const float* resf, u16* outb, int epi)
{
  gemm_core(A, BT, N, K, bias, resf, outb, epi);
}

__global__ __launch_bounds__(256) void gemm_qkv_kernel(
    const u16* A, const u16* BTq, size_t zstride, int K,
    const float* b0, const float* b1, const float* b2,
    u16* out0, u16* out1, u16* out2)
{
  const int z = blockIdx.z;
  const u16* BT = BTq + (size_t)z * zstride;
  const float* bias = (z == 0) ? b0 : (z == 1) ? b1 : b2;
  u16* outb = (z == 0) ? out0 : (z == 1) ? out1 : out2;
  gemm_core(A, BT, 512, K, bias, nullptr, outb, (z == 2) ? 3 : 0);
}

// ---------------- LayerNorm: bf16 in; bf16 out + optional f32 out -----------------
__global__ __launch_bounds__(256) void ln_kernel(
    const u16* __restrict__ y, const float* __restrict__ g, const float* __restrict__ bta,
    float* __restrict__ outf, u16* __restrict__ outb)
{
  const int lane = threadIdx.x & 63;
  const int row = blockIdx.x*4 + (threadIdx.x >> 6);
  const u16* yr = y + (size_t)row*D_ + lane*8;
  ushort4 a0 = *(const ushort4*)yr;
  ushort4 a1 = *(const ushort4*)(yr + 4);
  float v[8] = {b2f(a0.x), b2f(a0.y), b2f(a0.z), b2f(a0.w),
                b2f(a1.x), b2f(a1.y), b2f(a1.z), b2f(a1.w)};
  float s = 0.f;
#pragma unroll
  for (int e = 0; e < 8; e++) s += v[e];
#pragma unroll
  for (int m = 1; m < 64; m <<= 1) s += __shfl_xor(s, m);
  const float mu = s * (1.0f/512.0f);
  float q = 0.f;
#pragma unroll
  for (int e = 0; e < 8; e++) { float d = v[e] - mu; q += d*d; }
#pragma unroll
  for (int m = 1; m < 64; m <<= 1) q += __shfl_xor(q, m);
  const float rs = rsqrtf(q * (1.0f/512.0f) + 1e-12f);
  float4 g0 = *(const float4*)(g + lane*8);
  float4 g1 = *(const float4*)(g + lane*8 + 4);
  float4 b0 = *(const float4*)(bta + lane*8);
  float4 b1 = *(const float4*)(bta + lane*8 + 4);
  float gg[8] = {g0.x, g0.y, g0.z, g0.w, g1.x, g1.y, g1.z, g1.w};
  float bb[8] = {b0.x, b0.y, b0.z, b0.w, b1.x, b1.y, b1.z, b1.w};
  float o[8];
#pragma unroll
  for (int e = 0; e < 8; e++) o[e] = (v[e] - mu) * rs * gg[e] + bb[e];
  if (outf) {
    float4 w0 = {o[0], o[1], o[2], o[3]}, w1 = {o[4], o[5], o[6], o[7]};
    *(float4*)(outf + (size_t)row*D_ + lane*8)     = w0;
    *(float4*)(outf + (size_t)row*D_ + lane*8 + 4) = w1;
  }
  ushort4 u0 = {f2b(o[0]), f2b(o[1]), f2b(o[2]), f2b(o[3])};
  ushort4 u1 = {f2b(o[4]), f2b(o[5]), f2b(o[6]), f2b(o[7])};
  *(ushort4*)(outb + (size_t)row*D_ + lane*8)     = u0;
  *(ushort4*)(outb + (size_t)row*D_ + lane*8 + 4) = u1;
}

// ---------------- flash attention; inline lag-scale; grid (b, it, h) --------------
__global__ __launch_bounds__(256, 4) void attn_kernel(
    const u16* __restrict__ qb, const u16* __restrict__ kb, const u16* __restrict__ vt,
    const u16* __restrict__ pb16, const int* __restrict__ ts, u16* __restrict__ cb)
{
  __shared__ u16 QPs[64*64];                 // Q tile; wave's 16-row slice reused as P
  __shared__ u16 Ks[64*64], Vs[64*64], PBs[64*64];
  __shared__ float Tif[64], Tjf[64];
  const int b = blockIdx.x, it = blockIdx.y, h = blockIdx.z;
  const int i0 = it * 64;
  const int tid = threadIdx.x, wid = tid >> 6, lane = tid & 63;
  const int lr = lane & 15, quad = lane >> 4;
  const int l7 = lane & 7, l3 = lane >> 3;
  const int cc = (l7 ^ l3) * 8;
  const int f8 = lr & 7;
  const int rr = wid*8 + l3;

  const u16* qg  = qb + ((size_t)(b*S_ + i0))*D_ + h*DH_;
  const u16* kg  = kb + ((size_t)b*S_)*D_ + h*DH_;
  const u16* vg  = vt + ((size_t)(b*H_ + h)*DH_)*S_;
  const u16* pbg = pb16 + ((size_t)(h*S_ + i0))*S_;

  gld16(qg + (size_t)rr*D_ + cc,        QPs + wid*512);
  gld16(qg + (size_t)(rr+32)*D_ + cc,   QPs + 2048 + wid*512);
  if (tid < 64) Tif[tid] = (float)ts[b*S_ + i0 + tid] * (1.0f/60000.0f);
  __syncthreads();

  bf16x8 aq0 = *(const bf16x8*)(QPs + (wid*16 + lr)*64 + ((quad ^ f8) * 8));
  bf16x8 aq1 = *(const bf16x8*)(QPs + (wid*16 + lr)*64 + (((quad ^ f8) ^ 4) * 8));
  u16* Pw = QPs + wid*1024;

  float tis[4];
#pragma unroll
  for (int r = 0; r < 4; r++) tis[r] = Tif[wid*16 + quad*4 + r];

  f32x4 O[4]; float lacc[4];
#pragma unroll
  for (int dt = 0; dt < 4; dt++) O[dt] = (f32x4){0.f, 0.f, 0.f, 0.f};
#pragma unroll
  for (int r = 0; r < 4; r++) lacc[r] = 0.f;
  const int lrh = lr >> 3;

  for (int t8 = 0; t8 < 8; t8++) {
    const int j0 = t8 * 64;
    gld16(kg + (size_t)(j0+rr)*D_ + cc,      Ks + wid*512);
    gld16(kg + (size_t)(j0+rr+32)*D_ + cc,   Ks + 2048 + wid*512);
    gld16(vg + (size_t)rr*S_ + j0 + cc,      Vs + wid*512);
    gld16(vg + (size_t)(rr+32)*S_ + j0 + cc, Vs + 2048 + wid*512);
    gld16(pbg + (size_t)rr*S_ + j0 + cc,      PBs + wid*512);
    gld16(pbg + (size_t)(rr+32)*S_ + j0 + cc, PBs + 2048 + wid*512);
    if (tid < 64) Tjf[tid] = (float)ts[b*S_ + j0 + tid] * (1.0f/60000.0f);
    __syncthreads();

    f32x4 s[4];
#pragma unroll
    for (int jt = 0; jt < 4; jt++) {
      const u16* kr = Ks + (jt*16 + lr)*64;
      bf16x8 bk0 = *(const bf16x8*)(kr + ((quad ^ f8) * 8));
      bf16x8 bk1 = *(const bf16x8*)(kr + (((quad ^ f8) ^ 4) * 8));
      f32x4 z = (f32x4){0.f, 0.f, 0.f, 0.f};
      z = mfma16(aq0, bk0, z);
      z = mfma16(aq1, bk1, z);
      s[jt] = z;
    }
#pragma unroll
    for (int r = 0; r < 4; r++) {
      const int rowl = quad*4 + r;
      const int rbase = (wid*16 + rowl) * 64;
      const int r7 = rowl & 7;
      float pa = 0.f;
#pragma unroll
      for (int jt = 0; jt < 4; jt++) {
        const int idx = (((jt*2 + lrh) ^ r7) * 8) + l7;
        float lag = fmaxf(tis[r] - Tjf[idx], 0.0f);
        float inv = (lag + 1.0f) * __builtin_amdgcn_rcpf(fmaf(lag, 9.0f, 8.0f));
        float pbf = b2f(PBs[rbase + idx]);
        float p = __expf(fmaf(s[jt][r], inv, pbf));
        pa += p;
        Pw[rowl*64 + idx] = f2b(p);
      }
      lacc[r] += pa;
    }
    bf16x8 ap0 = *(const bf16x8*)(Pw + lr*64 + ((quad ^ f8) * 8));
    bf16x8 ap1 = *(const bf16x8*)(Pw + lr*64 + (((quad ^ f8) ^ 4) * 8));
#pragma unroll
    for (int dt = 0; dt < 4; dt++) {
      const u16* vr = Vs + (dt*16 + lr)*64;
      bf16x8 bv0 = *(const bf16x8*)(vr + ((quad ^ f8) * 8));
      bf16x8 bv1 = *(const bf16x8*)(vr + (((quad ^ f8) ^ 4) * 8));
      O[dt] = mfma16(ap0, bv0, O[dt]);
      O[dt] = mfma16(ap1, bv1, O[dt]);
    }
    __syncthreads();
  }

#pragma unroll
  for (int r = 0; r < 4; r++) {
    float sum = lacc[r];
#pragma unroll
    for (int m = 1; m < 16; m <<= 1) sum += __shfl_xor(sum, m);
    const float inv = __builtin_amdgcn_rcpf(sum);
    const size_t row = (size_t)(b*S_ + i0 + wid*16 + quad*4 + r);
#pragma unroll
    for (int dt = 0; dt < 4; dt++)
      cb[row*D_ + h*DH_ + dt*16 + lr] = f2b(O[dt][r] * inv);
  }
}

// ---------------- orchestration ---------------------------------------------------
extern "C" void kernel_launch(void* const* d_in, const int* in_sizes, int n_in,
                              void* d_out, int out_size, void* d_ws, size_t ws_size,
                              hipStream_t stream)
{
  const float* hidden = (const float*)d_in[0];
  const float* pbias  = (const float*)d_in[1];
  const int*   ts     = (const int*)d_in[2];
  const float* Wq = (const float*)d_in[3];   const float* bq  = (const float*)d_in[4];
  const float* Wk = (const float*)d_in[5];   const float* bk  = (const float*)d_in[6];
  const float* Wv = (const float*)d_in[7];   const float* bv  = (const float*)d_in[8];
  const float* Wo = (const float*)d_in[9];   const float* bo  = (const float*)d_in[10];
  const float* l1g = (const float*)d_in[11]; const float* l1b = (const float*)d_in[12];
  const float* Wi = (const float*)d_in[13];  const float* bi  = (const float*)d_in[14];
  const float* Wf = (const float*)d_in[15];  const float* bfw = (const float*)d_in[16];
  const float* l2g = (const float*)d_in[17]; const float* l2b = (const float*)d_in[18];

  char* w = (char*)d_ws;
  u16* xb    = (u16*)w; w += (size_t)M_*D_*2;
  u16* qb    = (u16*)w; w += (size_t)M_*D_*2;
  u16* kbuf  = (u16*)w; w += (size_t)M_*D_*2;
  u16* vtw   = (u16*)w; w += (size_t)M_*D_*2;
  u16* cbuf  = (u16*)w; w += (size_t)M_*D_*2;
  u16* attnb = (u16*)w; w += (size_t)M_*D_*2;
  u16* yb    = (u16*)w; w += (size_t)M_*D_*2;
  float* attnf = (float*)w; w += (size_t)M_*D_*4;
  u16* WqkvT = (u16*)w; w += (size_t)3*L_*D_*D_*2;
  u16* WoT   = (u16*)w; w += (size_t)L_*D_*D_*2;
  u16* WiT   = (u16*)w; w += (size_t)L_*D_*F_*2;
  u16* WfT   = (u16*)w; w += (size_t)L_*F_*D_*2;
  u16* pbb   = (u16*)w; w += (size_t)H_*S_*S_*2;
  u16* hb    = qb;   // alias: qb..cbuf = M_*F_ bf16; lifetimes disjoint

  float* x = (float*)d_out;

  const size_t WD = (size_t)D_*D_;
  const size_t WF = (size_t)D_*F_;
  dim3 tb(32, 8);

  transpose_w<<<dim3(16,16,L_), tb, 0, stream>>>(Wq, WqkvT,           D_, D_);
  transpose_w<<<dim3(16,16,L_), tb, 0, stream>>>(Wk, WqkvT + L_*WD,   D_, D_);
  transpose_w<<<dim3(16,16,L_), tb, 0, stream>>>(Wv, WqkvT + 2*L_*WD, D_, D_);
  transpose_w<<<dim3(16,16,L_), tb, 0, stream>>>(Wo, WoT,             D_, D_);
  transpose_w<<<dim3(64,16,L_), tb, 0, stream>>>(Wi, WiT,             D_, F_);
  transpose_w<<<dim3(16,64,L_), tb, 0, stream>>>(Wf, WfT,             F_, D_);
  prep_x<<<dim3(8192), dim3(256), 0, stream>>>(hidden, x, xb);
  prep_pb<<<dim3(H_*S_*S_/1024), dim3(256), 0, stream>>>(pbias, pbb);

  for (int l = 0; l < L_; l++) {
    gemm_qkv_kernel<<<dim3(128,4,3), dim3(256), 0, stream>>>(
        xb, WqkvT + l*WD, (size_t)L_*WD, D_,
        bq + l*D_, bk + l*D_, bv + l*D_, qb, kbuf, vtw);
    attn_kernel<<<dim3(B_,8,H_), dim3(256), 0, stream>>>(qb, kbuf, vtw, pbb, ts, cbuf);
    gemm_kernel<<<dim3(128,4), dim3(256), 0, stream>>>(
        cbuf, WoT + l*WD, D_, D_, bo + l*D_, x, yb, 1);
    ln_kernel<<<dim3(4096), dim3(256), 0, stream>>>(yb, l1g + l*D_, l1b + l*D_,
                                                    attnf, attnb);
    gemm_kernel<<<dim3(128,16), dim3(256), 0, stream>>>(
        attnb, WiT + l*WF, F_, D_, bi + l*F_, (const float*)nullptr, hb, 2);
    gemm_kernel<<<dim3(128,4), dim3(256), 0, stream>>>(
        hb, WfT + l*WF, D_, F_, bfw + l*D_, attnf, yb, 1);
    ln_kernel<<<dim3(4096), dim3(256), 0, stream>>>(yb, l2g + l*D_, l2b + l*D_, x, xb);
  }
}